// Round 2
// baseline (103.114 us; speedup 1.0000x reference)
//
#include <hip/hip_runtime.h>
#include <hip/hip_bf16.h>
#include <stdint.h>

typedef short short8 __attribute__((ext_vector_type(8)));
typedef float f32x4 __attribute__((ext_vector_type(4)));
typedef unsigned short ushort4v __attribute__((ext_vector_type(4)));

#define MDIM 8192
#define KDIM 1024
#define NDIM 1024
#define NKT  16   // K-tiles of 64

// ---------- helpers ----------

__device__ __forceinline__ unsigned short f2bf(float f) {
  union { float f; unsigned int u; } v; v.f = f;
  unsigned int u = v.u;
  u += 0x7fffu + ((u >> 16) & 1u);   // round-to-nearest-even
  return (unsigned short)(u >> 16);
}

__device__ __forceinline__ void load_lds16(const void* gsrc, void* ldst) {
  __builtin_amdgcn_global_load_lds(
      (__attribute__((address_space(1))) void*)gsrc,
      (__attribute__((address_space(3))) void*)ldst,
      16, 0, 0);
}

__device__ __forceinline__ float fast_sigmoid(float x) {
  return 1.0f / (1.0f + __expf(-x));
}

__device__ __forceinline__ float fast_tanh(float x) {
  x = fminf(30.0f, fmaxf(-30.0f, x));
  float e = __expf(-2.0f * x);
  return (1.0f - e) / (1.0f + e);
}

// ---------- conversion kernels ----------

__global__ void convert_h_kernel(const float* __restrict__ in,
                                 unsigned short* __restrict__ out, int n4) {
  int idx = blockIdx.x * blockDim.x + threadIdx.x;
  int stride = gridDim.x * blockDim.x;
  for (int i = idx; i < n4; i += stride) {
    float4 v = reinterpret_cast<const float4*>(in)[i];
    ushort4v o;
    o.x = f2bf(v.x); o.y = f2bf(v.y); o.z = f2bf(v.z); o.w = f2bf(v.w);
    reinterpret_cast<ushort4v*>(out)[i] = o;
  }
}

// w[k][n] f32 -> wT[gate][n][k] bf16 (transpose, LDS-tiled 64x64)
__global__ void convert_w_kernel(const float* __restrict__ w0,
                                 const float* __restrict__ w1,
                                 const float* __restrict__ w2,
                                 const float* __restrict__ w3,
                                 unsigned short* __restrict__ wT) {
  __shared__ float tile[64][65];
  int g = blockIdx.z;
  const float* w = (g == 0) ? w0 : (g == 1) ? w1 : (g == 2) ? w2 : w3;
  int k0 = blockIdx.y * 64;
  int n0 = blockIdx.x * 64;
  int tx = threadIdx.x;
  int ty = threadIdx.y;
#pragma unroll
  for (int j = 0; j < 16; ++j) {
    int kk = ty * 16 + j;
    tile[kk][tx] = w[(size_t)(k0 + kk) * NDIM + n0 + tx];
  }
  __syncthreads();
  unsigned short* dst = wT + (size_t)g * NDIM * KDIM;
#pragma unroll
  for (int j = 0; j < 16; ++j) {
    int nn = ty * 16 + j;
    dst[(size_t)(n0 + nn) * KDIM + k0 + tx] = f2bf(tile[tx][nn]);
  }
}

// ---------- fused 4-gate GEMM, 8-phase counted-vmcnt schedule ----------
//
// 512 threads = 8 waves (2M x 4N). Tile: 256 rows x (4 gates x 64 cols).
// Per wave: 128 rows x 16 cols x 4 gates; acc[4][8] f32x4 = 128 VGPR.
// LDS 128 KiB: 2 buffers x { A[kh][256][32k] 32KB + B[kh][4*64][32k] 32KB }.
// K-half-major 64B rows => ds_read_b128 fragments are a perfect 32-bank
// spread (no swizzle needed), and staging chunks are glds-contiguous.
// Pipeline: tile t+1 staged 2 loads/phase during tile t into the other
// buffer; vmcnt(4) only at K-half boundaries (never 0 in-loop).

#define LDS_BUF   65536
#define LDS_KH    16384
#define LDS_B_OFF 32768

#define STAGE_A(kh, h, nb_, tn) \
  load_lds16(hb + aoff + (h) * 262144 + (tn) * 128 + (kh) * 64, \
             lds + (nb_) + (kh) * LDS_KH + (h) * 8192 + tid * 16)
#define STAGE_B(kh, h, nb_, tn) \
  load_lds16(wb + ((h) ? boff1 : boff0) + (tn) * 128 + (kh) * 64, \
             lds + (nb_) + LDS_B_OFF + (kh) * LDS_KH + (h) * 8192 + tid * 16)

#define RD_A(cb_, kk, m) \
  (*(const short8*)(lds + (cb_) + (kk) * LDS_KH + \
                    (wr * 128 + (m) * 16 + r15) * 64 + hh * 16))
#define RD_B(cb_, kk, g) \
  (*(const short8*)(lds + (cb_) + LDS_B_OFF + (kk) * LDS_KH + \
                    ((g) * 64 + wc * 16 + r15) * 64 + hh * 16))

#define BARRIER() __builtin_amdgcn_s_barrier()
#define WAIT_LGKM0() do { \
    asm volatile("s_waitcnt lgkmcnt(0)" ::: "memory"); \
    __builtin_amdgcn_sched_barrier(0); } while (0)
#define WAIT_VM4() asm volatile("s_waitcnt vmcnt(4)" ::: "memory")

__global__ __launch_bounds__(512, 2) void lstm_fused_gemm(
    const unsigned short* __restrict__ hbf,   // [M][K] bf16
    const unsigned short* __restrict__ wT,    // [4][N][K] bf16
    const float* __restrict__ cprev,
    const float* __restrict__ b_i, const float* __restrict__ b_f,
    const float* __restrict__ b_g, const float* __restrict__ b_o,
    float* __restrict__ out)
{
  extern __shared__ unsigned char lds[];
  const int tid  = threadIdx.x;
  const int lane = tid & 63;
  const int wave = tid >> 6;
  const int wr = wave >> 2;   // 0..1 : rows wr*128..+128
  const int wc = wave & 3;    // 0..3 : cols wc*16..+16 (per gate)
  const int r15 = lane & 15;
  const int hh  = lane >> 4;

  // XCD-bijective swizzle: 512 blocks, 64 per XCD = 4 mb x 16 nb.
  int bid = blockIdx.x;
  int loc = bid >> 3;
  int mb = (bid & 7) * 4 + (loc >> 4);   // 0..31
  int nb = loc & 15;                     // 0..15
  int brow = mb * 256;
  int bcol = nb * 64;

  // per-thread staging offsets (bytes)
  const char* hb = (const char*)hbf;
  const char* wb = (const char*)wT;
  const int q  = tid & 3;
  const int sr = tid >> 2;  // 0..127
  const uint32_t aoff  = (uint32_t)((brow + sr) * 2048 + q * 16);
  const uint32_t boff0 = (uint32_t)((((sr >> 6)) * 1024 + bcol + (sr & 63)) * 2048 + q * 16);
  const uint32_t boff1 = (uint32_t)(((2 + (sr >> 6)) * 1024 + bcol + (sr & 63)) * 2048 + q * 16);

  f32x4 acc[4][8];
#pragma unroll
  for (int g = 0; g < 4; ++g)
#pragma unroll
    for (int m = 0; m < 8; ++m)
      acc[g][m] = (f32x4){0.f, 0.f, 0.f, 0.f};

  uint32_t cb = 0, nbuf = LDS_BUF;

  // prologue: stage tile 0 (order = consumption order)
  STAGE_A(0, 0, cb, 0); STAGE_A(0, 1, cb, 0);
  STAGE_B(0, 0, cb, 0); STAGE_B(0, 1, cb, 0);
  STAGE_A(1, 0, cb, 0); STAGE_A(1, 1, cb, 0);
  STAGE_B(1, 0, cb, 0); STAGE_B(1, 1, cb, 0);
  WAIT_VM4();          // Kh0 (A+B) landed; Kh1 may be in flight
  BARRIER();

  for (int t = 0; t < NKT; ++t) {
    const int tn = (t + 1) & (NKT - 1);  // t==15 wraps: harmless dummy loads

    // ---- phase 0: kk=0, m0-3 ----
    short8 B0 = RD_B(cb, 0, 0), B1 = RD_B(cb, 0, 1),
           B2 = RD_B(cb, 0, 2), B3 = RD_B(cb, 0, 3);
    short8 A0 = RD_A(cb, 0, 0), A1 = RD_A(cb, 0, 1),
           A2 = RD_A(cb, 0, 2), A3 = RD_A(cb, 0, 3);
    STAGE_A(0, 0, nbuf, tn); STAGE_A(0, 1, nbuf, tn);
    BARRIER();
    WAIT_LGKM0();
    __builtin_amdgcn_s_setprio(1);
    acc[0][0] = __builtin_amdgcn_mfma_f32_16x16x32_bf16(A0, B0, acc[0][0], 0, 0, 0);
    acc[1][0] = __builtin_amdgcn_mfma_f32_16x16x32_bf16(A0, B1, acc[1][0], 0, 0, 0);
    acc[2][0] = __builtin_amdgcn_mfma_f32_16x16x32_bf16(A0, B2, acc[2][0], 0, 0, 0);
    acc[3][0] = __builtin_amdgcn_mfma_f32_16x16x32_bf16(A0, B3, acc[3][0], 0, 0, 0);
    acc[0][1] = __builtin_amdgcn_mfma_f32_16x16x32_bf16(A1, B0, acc[0][1], 0, 0, 0);
    acc[1][1] = __builtin_amdgcn_mfma_f32_16x16x32_bf16(A1, B1, acc[1][1], 0, 0, 0);
    acc[2][1] = __builtin_amdgcn_mfma_f32_16x16x32_bf16(A1, B2, acc[2][1], 0, 0, 0);
    acc[3][1] = __builtin_amdgcn_mfma_f32_16x16x32_bf16(A1, B3, acc[3][1], 0, 0, 0);
    acc[0][2] = __builtin_amdgcn_mfma_f32_16x16x32_bf16(A2, B0, acc[0][2], 0, 0, 0);
    acc[1][2] = __builtin_amdgcn_mfma_f32_16x16x32_bf16(A2, B1, acc[1][2], 0, 0, 0);
    acc[2][2] = __builtin_amdgcn_mfma_f32_16x16x32_bf16(A2, B2, acc[2][2], 0, 0, 0);
    acc[3][2] = __builtin_amdgcn_mfma_f32_16x16x32_bf16(A2, B3, acc[3][2], 0, 0, 0);
    acc[0][3] = __builtin_amdgcn_mfma_f32_16x16x32_bf16(A3, B0, acc[0][3], 0, 0, 0);
    acc[1][3] = __builtin_amdgcn_mfma_f32_16x16x32_bf16(A3, B1, acc[1][3], 0, 0, 0);
    acc[2][3] = __builtin_amdgcn_mfma_f32_16x16x32_bf16(A3, B2, acc[2][3], 0, 0, 0);
    acc[3][3] = __builtin_amdgcn_mfma_f32_16x16x32_bf16(A3, B3, acc[3][3], 0, 0, 0);
    __builtin_amdgcn_s_setprio(0);
    BARRIER();

    // ---- phase 1: kk=0, m4-7 ----
    short8 A4 = RD_A(cb, 0, 4), A5 = RD_A(cb, 0, 5),
           A6 = RD_A(cb, 0, 6), A7 = RD_A(cb, 0, 7);
    STAGE_B(0, 0, nbuf, tn); STAGE_B(0, 1, nbuf, tn);
    BARRIER();
    WAIT_LGKM0();
    __builtin_amdgcn_s_setprio(1);
    acc[0][4] = __builtin_amdgcn_mfma_f32_16x16x32_bf16(A4, B0, acc[0][4], 0, 0, 0);
    acc[1][4] = __builtin_amdgcn_mfma_f32_16x16x32_bf16(A4, B1, acc[1][4], 0, 0, 0);
    acc[2][4] = __builtin_amdgcn_mfma_f32_16x16x32_bf16(A4, B2, acc[2][4], 0, 0, 0);
    acc[3][4] = __builtin_amdgcn_mfma_f32_16x16x32_bf16(A4, B3, acc[3][4], 0, 0, 0);
    acc[0][5] = __builtin_amdgcn_mfma_f32_16x16x32_bf16(A5, B0, acc[0][5], 0, 0, 0);
    acc[1][5] = __builtin_amdgcn_mfma_f32_16x16x32_bf16(A5, B1, acc[1][5], 0, 0, 0);
    acc[2][5] = __builtin_amdgcn_mfma_f32_16x16x32_bf16(A5, B2, acc[2][5], 0, 0, 0);
    acc[3][5] = __builtin_amdgcn_mfma_f32_16x16x32_bf16(A5, B3, acc[3][5], 0, 0, 0);
    acc[0][6] = __builtin_amdgcn_mfma_f32_16x16x32_bf16(A6, B0, acc[0][6], 0, 0, 0);
    acc[1][6] = __builtin_amdgcn_mfma_f32_16x16x32_bf16(A6, B1, acc[1][6], 0, 0, 0);
    acc[2][6] = __builtin_amdgcn_mfma_f32_16x16x32_bf16(A6, B2, acc[2][6], 0, 0, 0);
    acc[3][6] = __builtin_amdgcn_mfma_f32_16x16x32_bf16(A6, B3, acc[3][6], 0, 0, 0);
    acc[0][7] = __builtin_amdgcn_mfma_f32_16x16x32_bf16(A7, B0, acc[0][7], 0, 0, 0);
    acc[1][7] = __builtin_amdgcn_mfma_f32_16x16x32_bf16(A7, B1, acc[1][7], 0, 0, 0);
    acc[2][7] = __builtin_amdgcn_mfma_f32_16x16x32_bf16(A7, B2, acc[2][7], 0, 0, 0);
    acc[3][7] = __builtin_amdgcn_mfma_f32_16x16x32_bf16(A7, B3, acc[3][7], 0, 0, 0);
    __builtin_amdgcn_s_setprio(0);
    WAIT_VM4();   // retire this tile's Kh1 halves (needed next 2 phases)
    BARRIER();

    // ---- phase 2: kk=1, m0-3 ----
    B0 = RD_B(cb, 1, 0); B1 = RD_B(cb, 1, 1);
    B2 = RD_B(cb, 1, 2); B3 = RD_B(cb, 1, 3);
    A0 = RD_A(cb, 1, 0); A1 = RD_A(cb, 1, 1);
    A2 = RD_A(cb, 1, 2); A3 = RD_A(cb, 1, 3);
    STAGE_A(1, 0, nbuf, tn); STAGE_A(1, 1, nbuf, tn);
    BARRIER();
    WAIT_LGKM0();
    __builtin_amdgcn_s_setprio(1);
    acc[0][0] = __builtin_amdgcn_mfma_f32_16x16x32_bf16(A0, B0, acc[0][0], 0, 0, 0);
    acc[1][0] = __builtin_amdgcn_mfma_f32_16x16x32_bf16(A0, B1, acc[1][0], 0, 0, 0);
    acc[2][0] = __builtin_amdgcn_mfma_f32_16x16x32_bf16(A0, B2, acc[2][0], 0, 0, 0);
    acc[3][0] = __builtin_amdgcn_mfma_f32_16x16x32_bf16(A0, B3, acc[3][0], 0, 0, 0);
    acc[0][1] = __builtin_amdgcn_mfma_f32_16x16x32_bf16(A1, B0, acc[0][1], 0, 0, 0);
    acc[1][1] = __builtin_amdgcn_mfma_f32_16x16x32_bf16(A1, B1, acc[1][1], 0, 0, 0);
    acc[2][1] = __builtin_amdgcn_mfma_f32_16x16x32_bf16(A1, B2, acc[2][1], 0, 0, 0);
    acc[3][1] = __builtin_amdgcn_mfma_f32_16x16x32_bf16(A1, B3, acc[3][1], 0, 0, 0);
    acc[0][2] = __builtin_amdgcn_mfma_f32_16x16x32_bf16(A2, B0, acc[0][2], 0, 0, 0);
    acc[1][2] = __builtin_amdgcn_mfma_f32_16x16x32_bf16(A2, B1, acc[1][2], 0, 0, 0);
    acc[2][2] = __builtin_amdgcn_mfma_f32_16x16x32_bf16(A2, B2, acc[2][2], 0, 0, 0);
    acc[3][2] = __builtin_amdgcn_mfma_f32_16x16x32_bf16(A2, B3, acc[3][2], 0, 0, 0);
    acc[0][3] = __builtin_amdgcn_mfma_f32_16x16x32_bf16(A3, B0, acc[0][3], 0, 0, 0);
    acc[1][3] = __builtin_amdgcn_mfma_f32_16x16x32_bf16(A3, B1, acc[1][3], 0, 0, 0);
    acc[2][3] = __builtin_amdgcn_mfma_f32_16x16x32_bf16(A3, B2, acc[2][3], 0, 0, 0);
    acc[3][3] = __builtin_amdgcn_mfma_f32_16x16x32_bf16(A3, B3, acc[3][3], 0, 0, 0);
    __builtin_amdgcn_s_setprio(0);
    BARRIER();

    // ---- phase 3: kk=1, m4-7 ----
    A4 = RD_A(cb, 1, 4); A5 = RD_A(cb, 1, 5);
    A6 = RD_A(cb, 1, 6); A7 = RD_A(cb, 1, 7);
    STAGE_B(1, 0, nbuf, tn); STAGE_B(1, 1, nbuf, tn);
    BARRIER();
    WAIT_LGKM0();
    __builtin_amdgcn_s_setprio(1);
    acc[0][4] = __builtin_amdgcn_mfma_f32_16x16x32_bf16(A4, B0, acc[0][4], 0, 0, 0);
    acc[1][4] = __builtin_amdgcn_mfma_f32_16x16x32_bf16(A4, B1, acc[1][4], 0, 0, 0);
    acc[2][4] = __builtin_amdgcn_mfma_f32_16x16x32_bf16(A4, B2, acc[2][4], 0, 0, 0);
    acc[3][4] = __builtin_amdgcn_mfma_f32_16x16x32_bf16(A4, B3, acc[3][4], 0, 0, 0);
    acc[0][5] = __builtin_amdgcn_mfma_f32_16x16x32_bf16(A5, B0, acc[0][5], 0, 0, 0);
    acc[1][5] = __builtin_amdgcn_mfma_f32_16x16x32_bf16(A5, B1, acc[1][5], 0, 0, 0);
    acc[2][5] = __builtin_amdgcn_mfma_f32_16x16x32_bf16(A5, B2, acc[2][5], 0, 0, 0);
    acc[3][5] = __builtin_amdgcn_mfma_f32_16x16x32_bf16(A5, B3, acc[3][5], 0, 0, 0);
    acc[0][6] = __builtin_amdgcn_mfma_f32_16x16x32_bf16(A6, B0, acc[0][6], 0, 0, 0);
    acc[1][6] = __builtin_amdgcn_mfma_f32_16x16x32_bf16(A6, B1, acc[1][6], 0, 0, 0);
    acc[2][6] = __builtin_amdgcn_mfma_f32_16x16x32_bf16(A6, B2, acc[2][6], 0, 0, 0);
    acc[3][6] = __builtin_amdgcn_mfma_f32_16x16x32_bf16(A6, B3, acc[3][6], 0, 0, 0);
    acc[0][7] = __builtin_amdgcn_mfma_f32_16x16x32_bf16(A7, B0, acc[0][7], 0, 0, 0);
    acc[1][7] = __builtin_amdgcn_mfma_f32_16x16x32_bf16(A7, B1, acc[1][7], 0, 0, 0);
    acc[2][7] = __builtin_amdgcn_mfma_f32_16x16x32_bf16(A7, B2, acc[2][7], 0, 0, 0);
    acc[3][7] = __builtin_amdgcn_mfma_f32_16x16x32_bf16(A7, B3, acc[3][7], 0, 0, 0);
    __builtin_amdgcn_s_setprio(0);
    WAIT_VM4();   // retire next tile's Kh0 halves (A+B)
    BARRIER();

    uint32_t tmp = cb; cb = nbuf; nbuf = tmp;
  }

  // ---- fused LSTM epilogue ----
  // C/D layout: col = lane&15, row = (lane>>4)*4 + j.
  const size_t outC = (size_t)MDIM * NDIM;
  const int cc = bcol + wc * 16 + r15;
  const float bi = b_i[cc], bff = b_f[cc], bg = b_g[cc], bo = b_o[cc];
#pragma unroll
  for (int m = 0; m < 8; ++m) {
#pragma unroll
    for (int j = 0; j < 4; ++j) {
      int rr = brow + wr * 128 + m * 16 + hh * 4 + j;
      size_t base = (size_t)rr * NDIM + cc;
      float pi = acc[0][m][j] + bi;
      float pf = acc[1][m][j] + bff;
      float pg = acc[2][m][j] + bg;
      float po = acc[3][m][j] + bo;
      float iv = fast_sigmoid(pi);
      float fv = fast_sigmoid(pf);
      float gv = fast_tanh(pg);
      float ov = fast_sigmoid(po);
      float cp = fv * cprev[base] + iv * gv;
      float hp = ov * fast_tanh(cp);
      out[base] = hp;
      out[outC + base] = cp;
    }
  }
}

// ---------- launch ----------

extern "C" void kernel_launch(void* const* d_in, const int* in_sizes, int n_in,
                              void* d_out, int out_size, void* d_ws, size_t ws_size,
                              hipStream_t stream) {
  const float* hprev = (const float*)d_in[0];
  const float* cprev = (const float*)d_in[1];
  const float* w_hi  = (const float*)d_in[2];
  const float* b_hi  = (const float*)d_in[3];
  const float* w_hf  = (const float*)d_in[4];
  const float* b_hf  = (const float*)d_in[5];
  const float* w_hg  = (const float*)d_in[6];
  const float* b_hg  = (const float*)d_in[7];
  const float* w_ho  = (const float*)d_in[8];
  const float* b_ho  = (const float*)d_in[9];
  float* out = (float*)d_out;

  unsigned short* hbf = (unsigned short*)d_ws;
  unsigned short* wT  = (unsigned short*)((char*)d_ws + (size_t)MDIM * KDIM * 2);

  convert_h_kernel<<<2048, 256, 0, stream>>>(hprev, hbf, MDIM * KDIM / 4);
  convert_w_kernel<<<dim3(16, 16, 4), dim3(64, 4, 1), 0, stream>>>(
      w_hi, w_hf, w_hg, w_ho, wT);
  lstm_fused_gemm<<<512, 512, 131072, stream>>>(hbf, wT, cprev,
                                                b_hi, b_hf, b_hg, b_ho, out);
}

// Round 3
// 101.153 us; speedup vs baseline: 1.0194x; 1.0194x over previous
//
#include <hip/hip_runtime.h>
#include <hip/hip_bf16.h>
#include <stdint.h>

typedef short short8 __attribute__((ext_vector_type(8)));
typedef float f32x4 __attribute__((ext_vector_type(4)));
typedef unsigned short ushort4v __attribute__((ext_vector_type(4)));

#define MDIM 8192
#define KDIM 1024
#define NDIM 1024
#define NHALF 32   // K-halves of 32 elements (64 B)

// ---------- helpers ----------

__device__ __forceinline__ unsigned short f2bf(float f) {
  union { float f; unsigned int u; } v; v.f = f;
  unsigned int u = v.u;
  u += 0x7fffu + ((u >> 16) & 1u);
  return (unsigned short)(u >> 16);
}

__device__ __forceinline__ void load_lds16(const void* gsrc, void* ldst) {
  __builtin_amdgcn_global_load_lds(
      (__attribute__((address_space(1))) void*)gsrc,
      (__attribute__((address_space(3))) void*)ldst,
      16, 0, 0);
}

__device__ __forceinline__ float fast_sigmoid(float x) {
  return 1.0f / (1.0f + __expf(-x));
}

__device__ __forceinline__ float fast_tanh(float x) {
  x = fminf(30.0f, fmaxf(-30.0f, x));
  float e = __expf(-2.0f * x);
  return (1.0f - e) / (1.0f + e);
}

// ---------- conversion kernels ----------

__global__ void convert_h_kernel(const float* __restrict__ in,
                                 unsigned short* __restrict__ out, int n4) {
  int idx = blockIdx.x * blockDim.x + threadIdx.x;
  int stride = gridDim.x * blockDim.x;
  for (int i = idx; i < n4; i += stride) {
    float4 v = reinterpret_cast<const float4*>(in)[i];
    ushort4v o;
    o.x = f2bf(v.x); o.y = f2bf(v.y); o.z = f2bf(v.z); o.w = f2bf(v.w);
    reinterpret_cast<ushort4v*>(out)[i] = o;
  }
}

// w[k][n] f32 -> wT[gate][n][k] bf16 (transpose, LDS-tiled 64x64)
__global__ void convert_w_kernel(const float* __restrict__ w0,
                                 const float* __restrict__ w1,
                                 const float* __restrict__ w2,
                                 const float* __restrict__ w3,
                                 unsigned short* __restrict__ wT) {
  __shared__ float tile[64][65];
  int g = blockIdx.z;
  const float* w = (g == 0) ? w0 : (g == 1) ? w1 : (g == 2) ? w2 : w3;
  int k0 = blockIdx.y * 64;
  int n0 = blockIdx.x * 64;
  int tx = threadIdx.x;
  int ty = threadIdx.y;
#pragma unroll
  for (int j = 0; j < 16; ++j) {
    int kk = ty * 16 + j;
    tile[kk][tx] = w[(size_t)(k0 + kk) * NDIM + n0 + tx];
  }
  __syncthreads();
  unsigned short* dst = wT + (size_t)g * NDIM * KDIM;
#pragma unroll
  for (int j = 0; j < 16; ++j) {
    int nn = ty * 16 + j;
    dst[(size_t)(n0 + nn) * KDIM + k0 + tx] = f2bf(tile[tx][nn]);
  }
}

// ---------- fused 4-gate GEMM: 4-slot K-half ring, counted vmcnt ----------
//
// 512 threads = 8 waves (2M x 4N). Block tile: 256 rows x (4 gates x 64).
// K-half unit = 32 k-elems (64 B/row). Ring of 4 slots x 32 KB
// (A-Kh 16 KB + B-Kh 16 KB) = 128 KB, ALL offsets compile-time constants
// (loop unrolled 4 halves) so the backend can alias-disambiguate
// global_load_lds writes from ds_reads -> counted vmcnt survives.
// Flight: during half h stage half h+3; vmcnt(8) per half boundary.
// Slot layout: [pair=row>>1][128 B], 16B-chunk slot =
//   (((row&1)<<2)|chunk) ^ (pair&7)  -> 2 lanes/bank on every
// ds_read_b128 quarter-wave (conflict-free); linear for glds staging
// (swizzle folded into the per-thread GLOBAL source address).

#define SLOT_SZ 32768
#define S0 0
#define S1 32768
#define S2 65536
#define S3 98304

#define BARRIER() __builtin_amdgcn_s_barrier()
#define WAIT_LGKM0() do { \
    asm volatile("s_waitcnt lgkmcnt(0)" ::: "memory"); \
    __builtin_amdgcn_sched_barrier(0); } while (0)
#define WAIT_VM8() asm volatile("s_waitcnt vmcnt(8)" ::: "memory")

#define STAGE_A_H(koff, T) do { \
    load_lds16(hb + srcA0 + (koff), lds + (T) + tid * 16); \
    load_lds16(hb + srcA1 + (koff), lds + (T) + 8192 + tid * 16); } while (0)
#define STAGE_B_H(koff, T) do { \
    load_lds16(wb + srcB0 + (koff), lds + (T) + 16384 + tid * 16); \
    load_lds16(wb + srcB1 + (koff), lds + (T) + 16384 + 8192 + tid * 16); } while (0)

#define MFMA16(mb_) do { \
  _Pragma("unroll") \
  for (int mi = 0; mi < 4; ++mi) { \
    _Pragma("unroll") \
    for (int g = 0; g < 4; ++g) \
      acc[g][(mb_) + mi] = __builtin_amdgcn_mfma_f32_16x16x32_bf16( \
          Af[mi], Bf[g], acc[g][(mb_) + mi], 0, 0, 0); \
  } } while (0)

// One K-half: 2 phases of 16 MFMA. S = this half's slot, T = stage slot.
#define HALF(hidx, S, T) do { \
    const uint32_t ko = (uint32_t)(((hidx) + 3) & (NHALF - 1)) * 64; \
    /* phase A: read B0-3 + A0-3, stage next A, mfma m0-3 */ \
    short8 Bf[4], Af[4]; \
    _Pragma("unroll") \
    for (int g = 0; g < 4; ++g) \
      Bf[g] = *(const short8*)(lds + (S) + 16384 + g * 4096 + b_off); \
    _Pragma("unroll") \
    for (int mi = 0; mi < 4; ++mi) \
      Af[mi] = *(const short8*)(lds + (S) + a_off + mi * 1024); \
    STAGE_A_H(ko, T); \
    BARRIER(); \
    WAIT_LGKM0(); \
    __builtin_amdgcn_s_setprio(1); \
    MFMA16(0); \
    __builtin_amdgcn_s_setprio(0); \
    BARRIER(); \
    /* phase B: read A4-7, stage next B, mfma m4-7 */ \
    _Pragma("unroll") \
    for (int mi = 0; mi < 4; ++mi) \
      Af[mi] = *(const short8*)(lds + (S) + a_off + (4 + mi) * 1024); \
    STAGE_B_H(ko, T); \
    BARRIER(); \
    WAIT_LGKM0(); \
    __builtin_amdgcn_s_setprio(1); \
    MFMA16(4); \
    __builtin_amdgcn_s_setprio(0); \
    WAIT_VM8(); \
    BARRIER(); } while (0)

__global__ __launch_bounds__(512, 2) void lstm_fused_gemm(
    const unsigned short* __restrict__ hbf,   // [M][K] bf16
    const unsigned short* __restrict__ wT,    // [4][N][K] bf16
    const float* __restrict__ cprev,
    const float* __restrict__ b_i, const float* __restrict__ b_f,
    const float* __restrict__ b_g, const float* __restrict__ b_o,
    float* __restrict__ out)
{
  extern __shared__ unsigned char lds[];
  const int tid  = threadIdx.x;
  const int lane = tid & 63;
  const int wave = tid >> 6;
  const int wr = wave >> 2;   // 0..1 : rows wr*128..+128
  const int wc = wave & 3;    // 0..3 : cols wc*16..+16 per gate
  const int r15 = lane & 15;
  const int hh  = lane >> 4;

  // XCD-bijective swizzle: 512 blocks, 64/XCD = 4 mb x 16 nb.
  int bid = blockIdx.x;
  int loc = bid >> 3;
  int mb = (bid & 7) * 4 + (loc >> 4);
  int nb = loc & 15;
  int brow = mb * 256;
  int bcol = nb * 64;

  const char* hb = (const char*)hbf;
  const char* wb = (const char*)wT;

  // ---- staging source offsets (swizzle folded into global addr) ----
  // dest (pair p, 16B-slot s) holds row 2p+(u>>2), chunk u&3, u = s^(p&7).
  const int sD = tid & 7;
  const int pB = tid >> 3;                  // pair base (j adds 64)
  const int u  = sD ^ (pB & 7);             // j*64 = 0 mod 8
  const int c16 = (u & 3) * 16;
  const int rA0 = 2 * pB + (u >> 2);        // j=0 row
  const int rA1 = 128 + rA0;                // j=1 row
  const uint32_t srcA0 = (uint32_t)(brow + rA0) * 2048 + c16;
  const uint32_t srcA1 = (uint32_t)(brow + rA1) * 2048 + c16;
  const uint32_t srcB0 = (uint32_t)((rA0 >> 6) * 1024 + bcol + (rA0 & 63)) * 2048 + c16;
  const uint32_t srcB1 = (uint32_t)((rA1 >> 6) * 1024 + bcol + (rA1 & 63)) * 2048 + c16;

  // ---- fragment read offsets ----
  const int slot16 = (((((r15 & 1) << 2) | hh) ^ (r15 >> 1)) * 16);
  const uint32_t a_off = (uint32_t)(wr * 64 + (r15 >> 1)) * 128 + slot16;
  const uint32_t b_off = (uint32_t)(wc * 8 + (r15 >> 1)) * 128 + slot16;

  f32x4 acc[4][8];
#pragma unroll
  for (int g = 0; g < 4; ++g)
#pragma unroll
    for (int m = 0; m < 8; ++m)
      acc[g][m] = (f32x4){0.f, 0.f, 0.f, 0.f};

  // ---- prologue: stage halves 0,1,2 ----
  STAGE_A_H(0, S0);       STAGE_B_H(0, S0);
  STAGE_A_H(64, S1);      STAGE_B_H(64, S1);
  STAGE_A_H(128, S2);     STAGE_B_H(128, S2);
  WAIT_VM8();             // half 0 (oldest 4) landed
  BARRIER();

  for (int h = 0; h < NHALF; h += 4) {
    HALF(h + 0, S0, S3);
    HALF(h + 1, S1, S0);
    HALF(h + 2, S2, S1);
    HALF(h + 3, S3, S2);
  }

  // ---- fused LSTM epilogue ----
  // C/D layout: col = lane&15, row = (lane>>4)*4 + j.
  const size_t outC = (size_t)MDIM * NDIM;
  const int cc = bcol + wc * 16 + r15;
  const float bi = b_i[cc], bff = b_f[cc], bg = b_g[cc], bo = b_o[cc];
#pragma unroll
  for (int m = 0; m < 8; ++m) {
#pragma unroll
    for (int j = 0; j < 4; ++j) {
      int rr = brow + wr * 128 + m * 16 + hh * 4 + j;
      size_t base = (size_t)rr * NDIM + cc;
      float pi = acc[0][m][j] + bi;
      float pf = acc[1][m][j] + bff;
      float pg = acc[2][m][j] + bg;
      float po = acc[3][m][j] + bo;
      float iv = fast_sigmoid(pi);
      float fv = fast_sigmoid(pf);
      float gv = fast_tanh(pg);
      float ov = fast_sigmoid(po);
      float cp = fv * cprev[base] + iv * gv;
      float hp = ov * fast_tanh(cp);
      out[base] = hp;
      out[outC + base] = cp;
    }
  }
}

// ---------- launch ----------

extern "C" void kernel_launch(void* const* d_in, const int* in_sizes, int n_in,
                              void* d_out, int out_size, void* d_ws, size_t ws_size,
                              hipStream_t stream) {
  const float* hprev = (const float*)d_in[0];
  const float* cprev = (const float*)d_in[1];
  const float* w_hi  = (const float*)d_in[2];
  const float* b_hi  = (const float*)d_in[3];
  const float* w_hf  = (const float*)d_in[4];
  const float* b_hf  = (const float*)d_in[5];
  const float* w_hg  = (const float*)d_in[6];
  const float* b_hg  = (const float*)d_in[7];
  const float* w_ho  = (const float*)d_in[8];
  const float* b_ho  = (const float*)d_in[9];
  float* out = (float*)d_out;

  unsigned short* hbf = (unsigned short*)d_ws;
  unsigned short* wT  = (unsigned short*)((char*)d_ws + (size_t)MDIM * KDIM * 2);

  convert_h_kernel<<<2048, 256, 0, stream>>>(hprev, hbf, MDIM * KDIM / 4);
  convert_w_kernel<<<dim3(16, 16, 4), dim3(64, 4, 1), 0, stream>>>(
      w_hi, w_hf, w_hg, w_ho, wT);
  lstm_fused_gemm<<<512, 512, 131072, stream>>>(hbf, wT, cprev,
                                                b_hi, b_hf, b_hg, b_ho, out);
}

// Round 4
// 99.598 us; speedup vs baseline: 1.0353x; 1.0156x over previous
//
#include <hip/hip_runtime.h>
#include <hip/hip_bf16.h>
#include <stdint.h>

typedef short short8 __attribute__((ext_vector_type(8)));
typedef float f32x4 __attribute__((ext_vector_type(4)));
typedef unsigned short ushort4v __attribute__((ext_vector_type(4)));

#define MDIM 8192
#define KDIM 1024
#define NDIM 1024
#define NKT  16    // K-tiles of 64

// ---------- helpers ----------

__device__ __forceinline__ unsigned short f2bf(float f) {
  union { float f; unsigned int u; } v; v.f = f;
  unsigned int u = v.u;
  u += 0x7fffu + ((u >> 16) & 1u);
  return (unsigned short)(u >> 16);
}

__device__ __forceinline__ void load_lds16(const void* gsrc, void* ldst) {
  __builtin_amdgcn_global_load_lds(
      (__attribute__((address_space(1))) void*)gsrc,
      (__attribute__((address_space(3))) void*)ldst,
      16, 0, 0);
}

__device__ __forceinline__ float fast_sigmoid(float x) {
  return 1.0f / (1.0f + __expf(-x));
}

__device__ __forceinline__ float fast_tanh(float x) {
  x = fminf(30.0f, fmaxf(-30.0f, x));
  float e = __expf(-2.0f * x);
  return (1.0f - e) / (1.0f + e);
}

// ---------- conversion kernels (write TILED bf16 workspace) ----------

// hprev f32 [M][K] -> A_t[kt][M][64] bf16 (K-tile panels, 128 B rows)
__global__ void convert_h_tiled(const float* __restrict__ in,
                                unsigned short* __restrict__ out, int nchunk) {
  int idx = blockIdx.x * blockDim.x + threadIdx.x;
  int stride = gridDim.x * blockDim.x;
  for (int i = idx; i < nchunk; i += stride) {
    int r = i >> 7;          // row
    int kc8 = i & 127;       // 8-elem chunk within row
    const float4* src = reinterpret_cast<const float4*>(in + (size_t)r * KDIM + kc8 * 8);
    float4 v0 = src[0], v1 = src[1];
    short8 o;
    o[0] = (short)f2bf(v0.x); o[1] = (short)f2bf(v0.y);
    o[2] = (short)f2bf(v0.z); o[3] = (short)f2bf(v0.w);
    o[4] = (short)f2bf(v1.x); o[5] = (short)f2bf(v1.y);
    o[6] = (short)f2bf(v1.z); o[7] = (short)f2bf(v1.w);
    int kt = kc8 >> 3;
    int c8 = kc8 & 7;
    // dst 16B chunk index: (kt*M + r)*8 + c8
    reinterpret_cast<short8*>(out)[((size_t)kt * MDIM + r) * 8 + c8] = o;
  }
}

// w[k][n] f32 -> B_t[kt][g][N][64] bf16 (transpose + tile)
__global__ void convert_w_tiled(const float* __restrict__ w0,
                                const float* __restrict__ w1,
                                const float* __restrict__ w2,
                                const float* __restrict__ w3,
                                unsigned short* __restrict__ out) {
  __shared__ float tile[64][65];
  int g = blockIdx.z;
  const float* w = (g == 0) ? w0 : (g == 1) ? w1 : (g == 2) ? w2 : w3;
  int kt = blockIdx.y;           // K-tile (64)
  int k0 = kt * 64;
  int n0 = blockIdx.x * 64;
  int tx = threadIdx.x;
  int ty = threadIdx.y;
#pragma unroll
  for (int j = 0; j < 16; ++j) {
    int kk = ty * 16 + j;
    tile[kk][tx] = w[(size_t)(k0 + kk) * NDIM + n0 + tx];
  }
  __syncthreads();
#pragma unroll
  for (int j = 0; j < 16; ++j) {
    int nn = ty * 16 + j;
    // dst elem: ((kt*4+g)*N + n0+nn)*64 + tx   (row = 128 B, contiguous in tx)
    out[(((size_t)kt * 4 + g) * NDIM + n0 + nn) * 64 + tx] = f2bf(tile[tx][nn]);
  }
}

// ---------- fused 4-gate GEMM, double-buffered, coalesced staging ----------
//
// 512 threads = 8 waves (2M x 4N). Block tile: 256 rows x (4 gates x 64).
// LDS: 2 buffers x 64 KB { A[256][128B] + B[4*64][128B] }, XOR chunk
// swizzle (chunk c of row r stored at slot c^(r&7)) -> 2-way (free) bank
// pattern on all ds_read_b128; swizzle folded into the GLOBAL source
// address, which stays CONTIGUOUS per wave-instr (permutes within 128 B
// lines only) because the workspace is K-tile-panel tiled.
// Schedule per K-tile: 4 phases x 16 MFMA; stage next tile's A in P0,
// B in P1 (2-3 phase lead); one vmcnt(0) at tile end (loads long landed).

#define BUF0 0
#define BUF1 65536

#define BARRIER() __builtin_amdgcn_s_barrier()
#define WAIT_LGKM0() do { \
    asm volatile("s_waitcnt lgkmcnt(0)" ::: "memory"); \
    __builtin_amdgcn_sched_barrier(0); } while (0)
#define WAIT_VM0() asm volatile("s_waitcnt vmcnt(0)" ::: "memory")

// stage 2 consecutive 64-row groups of A (j0, j0+1) of K-tile byte-offset kA
#define STAGE_A2(T, kA, j0) do { \
    load_lds16(ab + srcA + (kA) + (j0) * 8192,       lds + (T) + (j0) * 8192 + tid * 16); \
    load_lds16(ab + srcA + (kA) + ((j0) + 1) * 8192, lds + (T) + ((j0) + 1) * 8192 + tid * 16); } while (0)
// stage 2 gates of B (g = j0, j0+1) of K-tile byte-offset kB
#define STAGE_B2(T, kB, j0) do { \
    load_lds16(bb + srcB + (kB) + (j0) * 131072,       lds + (T) + 32768 + (j0) * 8192 + tid * 16); \
    load_lds16(bb + srcB + (kB) + ((j0) + 1) * 131072, lds + (T) + 32768 + ((j0) + 1) * 8192 + tid * 16); } while (0)

#define RD_A(S, m, s) (*(const short8*)(lds + (S) + a_base + (m) * 2048 + (s)))
#define RD_B(S, g, s) (*(const short8*)(lds + (S) + b_base + (g) * 8192 + (s)))

#define MFMA16(mb_) do { \
  _Pragma("unroll") \
  for (int mi = 0; mi < 4; ++mi) { \
    _Pragma("unroll") \
    for (int g = 0; g < 4; ++g) \
      acc[g][(mb_) + mi] = __builtin_amdgcn_mfma_f32_16x16x32_bf16( \
          Af[mi], Bf[g], acc[g][(mb_) + mi], 0, 0, 0); \
  } } while (0)

// One K-tile: cur buffer CUR, stage next tile into NXT (kA/kB byte offsets)
#define TILE(CUR, NXT, kA, kB) do { \
    short8 Af[4], Bf[4]; \
    /* P0: B g0-3 kk0 + A m0-3 kk0; stage next A0-3 */ \
    _Pragma("unroll") for (int g = 0; g < 4; ++g) Bf[g] = RD_B(CUR, g, s0); \
    _Pragma("unroll") for (int mi = 0; mi < 4; ++mi) Af[mi] = RD_A(CUR, mi, s0); \
    STAGE_A2(NXT, kA, 0); STAGE_A2(NXT, kA, 2); \
    BARRIER(); WAIT_LGKM0(); \
    __builtin_amdgcn_s_setprio(1); MFMA16(0); __builtin_amdgcn_s_setprio(0); \
    BARRIER(); \
    /* P1: A m4-7 kk0 (B reused); stage next B0-3 */ \
    _Pragma("unroll") for (int mi = 0; mi < 4; ++mi) Af[mi] = RD_A(CUR, 4 + mi, s0); \
    STAGE_B2(NXT, kB, 0); STAGE_B2(NXT, kB, 2); \
    BARRIER(); WAIT_LGKM0(); \
    __builtin_amdgcn_s_setprio(1); MFMA16(4); __builtin_amdgcn_s_setprio(0); \
    BARRIER(); \
    /* P2: B kk1 + A m0-3 kk1 */ \
    _Pragma("unroll") for (int g = 0; g < 4; ++g) Bf[g] = RD_B(CUR, g, s1); \
    _Pragma("unroll") for (int mi = 0; mi < 4; ++mi) Af[mi] = RD_A(CUR, mi, s1); \
    BARRIER(); WAIT_LGKM0(); \
    __builtin_amdgcn_s_setprio(1); MFMA16(0); __builtin_amdgcn_s_setprio(0); \
    BARRIER(); \
    /* P3: A m4-7 kk1; drain next tile's stages (issued >=2 phases ago) */ \
    _Pragma("unroll") for (int mi = 0; mi < 4; ++mi) Af[mi] = RD_A(CUR, 4 + mi, s1); \
    BARRIER(); WAIT_LGKM0(); \
    __builtin_amdgcn_s_setprio(1); MFMA16(4); __builtin_amdgcn_s_setprio(0); \
    WAIT_VM0(); \
    BARRIER(); } while (0)

__global__ __launch_bounds__(512, 2) void lstm_fused_gemm(
    const unsigned short* __restrict__ At,    // [16][M][64] bf16
    const unsigned short* __restrict__ Bt,    // [16][4][N][64] bf16
    const float* __restrict__ cprev,
    const float* __restrict__ b_i, const float* __restrict__ b_f,
    const float* __restrict__ b_g, const float* __restrict__ b_o,
    float* __restrict__ out)
{
  extern __shared__ unsigned char lds[];
  const int tid  = threadIdx.x;
  const int lane = tid & 63;
  const int wave = tid >> 6;
  const int wr = wave >> 2;   // 0..1 : rows wr*128..+128
  const int wc = wave & 3;    // 0..3 : cols wc*16..+16 per gate
  const int r15 = lane & 15;
  const int hh  = lane >> 4;

  // XCD-bijective swizzle: 512 blocks, 64/XCD = 4 mb x 16 nb.
  int bid = blockIdx.x;
  int loc = bid >> 3;
  int mb = (bid & 7) * 4 + (loc >> 4);
  int nb = loc & 15;
  int brow = mb * 256;
  int bcol = nb * 64;

  const char* ab = (const char*)At;
  const char* bb = (const char*)Bt;

  // ---- staging source offsets (contiguous per wave; swizzle within lines) ----
  const int rloc = tid >> 3;                       // 0..63 row-within-group
  const int cx = (((tid & 7) ^ (rloc & 7)) << 4);  // pre-swizzled chunk
  const uint32_t srcA = (uint32_t)(brow + rloc) * 128 + cx;
  const uint32_t srcB = (uint32_t)(bcol + rloc) * 128 + cx;

  // ---- fragment read offsets ----
  const int s0 = ((hh ^ (r15 & 7)) << 4);   // kk=0 chunk slot (bytes)
  const int s1 = s0 ^ 64;                   // kk=1
  const uint32_t a_base = (uint32_t)(wr * 128 + r15) * 128;
  const uint32_t b_base = 32768u + (uint32_t)(wc * 16 + r15) * 128;

  f32x4 acc[4][8];
#pragma unroll
  for (int g = 0; g < 4; ++g)
#pragma unroll
    for (int m = 0; m < 8; ++m)
      acc[g][m] = (f32x4){0.f, 0.f, 0.f, 0.f};

  // ---- prologue: stage tile 0 into BUF0 ----
  STAGE_A2(BUF0, 0, 0); STAGE_A2(BUF0, 0, 2);
  STAGE_B2(BUF0, 0, 0); STAGE_B2(BUF0, 0, 2);
  WAIT_VM0();
  BARRIER();

  for (int it = 0; it < NKT / 2; ++it) {
    const uint32_t t1 = 2 * it + 1;
    const uint32_t t2 = (2 * it + 2) & (NKT - 1);  // last wraps: dummy stage
    {
      const uint32_t kA = t1 << 20, kB = t1 << 19;  // A panel 1 MB, B panel 512 KB
      TILE(BUF0, BUF1, kA, kB);
    }
    {
      const uint32_t kA = t2 << 20, kB = t2 << 19;
      TILE(BUF1, BUF0, kA, kB);
    }
  }

  // ---- fused LSTM epilogue ----
  // C/D layout: col = lane&15, row = (lane>>4)*4 + j.
  const size_t outC = (size_t)MDIM * NDIM;
  const int cc = bcol + wc * 16 + r15;
  const float bi = b_i[cc], bff = b_f[cc], bg = b_g[cc], bo = b_o[cc];
#pragma unroll
  for (int m = 0; m < 8; ++m) {
#pragma unroll
    for (int j = 0; j < 4; ++j) {
      int rr = brow + wr * 128 + m * 16 + hh * 4 + j;
      size_t base = (size_t)rr * NDIM + cc;
      float pi = acc[0][m][j] + bi;
      float pf = acc[1][m][j] + bff;
      float pg = acc[2][m][j] + bg;
      float po = acc[3][m][j] + bo;
      float iv = fast_sigmoid(pi);
      float fv = fast_sigmoid(pf);
      float gv = fast_tanh(pg);
      float ov = fast_sigmoid(po);
      float cp = fv * cprev[base] + iv * gv;
      float hp = ov * fast_tanh(cp);
      out[base] = hp;
      out[outC + base] = cp;
    }
  }
}

// ---------- launch ----------

extern "C" void kernel_launch(void* const* d_in, const int* in_sizes, int n_in,
                              void* d_out, int out_size, void* d_ws, size_t ws_size,
                              hipStream_t stream) {
  const float* hprev = (const float*)d_in[0];
  const float* cprev = (const float*)d_in[1];
  const float* w_hi  = (const float*)d_in[2];
  const float* b_hi  = (const float*)d_in[3];
  const float* w_hf  = (const float*)d_in[4];
  const float* b_hf  = (const float*)d_in[5];
  const float* w_hg  = (const float*)d_in[6];
  const float* b_hg  = (const float*)d_in[7];
  const float* w_ho  = (const float*)d_in[8];
  const float* b_ho  = (const float*)d_in[9];
  float* out = (float*)d_out;

  // workspace: [0,16MB) A_t tiled bf16; [16MB,24MB) B_t tiled bf16
  unsigned short* At = (unsigned short*)d_ws;
  unsigned short* Bt = (unsigned short*)((char*)d_ws + (size_t)NKT * MDIM * 64 * 2);

  convert_h_tiled<<<2048, 256, 0, stream>>>(hprev, At, MDIM * KDIM / 8);
  convert_w_tiled<<<dim3(16, 16, 4), dim3(64, 4, 1), 0, stream>>>(
      w_hi, w_hf, w_hg, w_ho, Bt);
  lstm_fused_gemm<<<512, 512, 131072, stream>>>(At, Bt, cprev,
                                                b_hi, b_hf, b_hg, b_ho, out);
}